// Round 2
// baseline (229.454 us; speedup 1.0000x reference)
//
#include <hip/hip_runtime.h>
#include <hip/hip_bf16.h>

// Self-attention, N=8192, C=256, fp32 in/out, bf16 MFMA internally.
// proj (Q,K,V bf16; V transposed; Q pre-scaled by log2e/16)
//   -> flash attention (Qtile=128 = 4 waves x 32 rows, KV split 8-way,
//      global_load_lds staging, defer-rescale, ones-MFMA row sums)
//   -> combine (merge 8 splits, divide by l).
//
// ws: [0,4Mi) qb bf16[8192][256]
//     [4Mi,8Mi) kb bf16[8192][256]
//     [8Mi,12Mi) vt bf16[256][8192]
//     [12Mi,44Mi) Opart bf16[8][8192][256]
//     [44Mi,+256Ki) Mpart f32[8][8192]
//     [+256Ki,+512Ki) Lpart f32[8][8192]     total 44.5 MiB

typedef short short8 __attribute__((ext_vector_type(8)));
typedef float f32x4 __attribute__((ext_vector_type(4)));

#define AS1 __attribute__((address_space(1)))
#define AS3 __attribute__((address_space(3)))

static __device__ __forceinline__ void gl_lds16(const void* g, void* l) {
    __builtin_amdgcn_global_load_lds((const AS1 unsigned int*)g,
                                     (AS3 unsigned int*)l, 16, 0, 0);
}

static __device__ __forceinline__ unsigned short f2bf(float f) {
    __hip_bfloat16 h = __float2bfloat16(f);
    return __builtin_bit_cast(unsigned short, h);
}
static __device__ __forceinline__ float bf2f(unsigned short u) {
    unsigned x = ((unsigned)u) << 16;
    return __builtin_bit_cast(float, x);
}
static __device__ __forceinline__ float exp2_fast(float x) {
    float r; asm("v_exp_f32 %0, %1" : "=v"(r) : "v"(x)); return r;
}

static __device__ __forceinline__ short8 pack8(float4 a, float4 b) {
    short8 v;
    v[0] = (short)f2bf(a.x); v[1] = (short)f2bf(a.y);
    v[2] = (short)f2bf(a.z); v[3] = (short)f2bf(a.w);
    v[4] = (short)f2bf(b.x); v[5] = (short)f2bf(b.y);
    v[6] = (short)f2bf(b.z); v[7] = (short)f2bf(b.w);
    return v;
}

// ---------------- projection (unchanged from round 1) ----------------------
__global__ __launch_bounds__(256) void proj_kernel(
    const float* __restrict__ x, const float* __restrict__ Wq,
    const float* __restrict__ Wk, const float* __restrict__ Wv,
    unsigned short* __restrict__ qb, unsigned short* __restrict__ kb,
    unsigned short* __restrict__ vt)
{
    const int mb = blockIdx.x, nb = blockIdx.y;
    __shared__ unsigned short xs[64 * 256];
    __shared__ unsigned short wsh[64 * 256];
    const int tid = threadIdx.x;
    const int wid = tid >> 6, lane = tid & 63;
    const int l15 = lane & 15, kg = lane >> 4;

    for (int i = 0; i < 8; ++i) {
        int id = i * 256 + tid;
        int r = id >> 5, c = id & 31;
        {
            const float* g = x + (size_t)(mb * 64 + r) * 256 + c * 8;
            float4 f0 = *(const float4*)g, f1 = *(const float4*)(g + 4);
            *(short8*)&xs[r * 256 + ((c ^ (r & 7)) * 8)] = pack8(f0, f1);
        }
        {
            const float* g = Wq + (size_t)(nb * 64 + r) * 256 + c * 8;
            float4 f0 = *(const float4*)g, f1 = *(const float4*)(g + 4);
            *(short8*)&wsh[r * 256 + ((c ^ (r & 7)) * 8)] = pack8(f0, f1);
        }
    }
    __syncthreads();

    const int arow = wid * 16 + l15;
    short8 a[8];
#pragma unroll
    for (int ks = 0; ks < 8; ++ks)
        a[ks] = *(const short8*)&xs[arow * 256 + (((ks * 4 + kg) ^ (arow & 7)) * 8)];

    for (int w = 0; w < 3; ++w) {
        const float scale = (w == 0) ? 0.09016844005555f : 1.0f; // log2(e)/16
#pragma unroll
        for (int nt = 0; nt < 4; ++nt) {
            f32x4 acc = {0.f, 0.f, 0.f, 0.f};
            const int brow = nt * 16 + l15;
#pragma unroll
            for (int ks = 0; ks < 8; ++ks) {
                short8 b = *(const short8*)&wsh[brow * 256 + (((ks * 4 + kg) ^ (brow & 7)) * 8)];
                acc = __builtin_amdgcn_mfma_f32_16x16x32_bf16(a[ks], b, acc, 0, 0, 0);
            }
            const int gcol = nb * 64 + nt * 16 + l15;
#pragma unroll
            for (int r = 0; r < 4; ++r) {
                const int grow = mb * 64 + wid * 16 + kg * 4 + r;
                unsigned short h = f2bf(acc[r] * scale);
                if (w == 0)      qb[(size_t)grow * 256 + gcol] = h;
                else if (w == 1) kb[(size_t)grow * 256 + gcol] = h;
                else             vt[(size_t)gcol * 8192 + grow] = h;
            }
        }
        if (w < 2) {
            __syncthreads();
            const float* Wn = (w == 0) ? Wk : Wv;
            for (int i = 0; i < 8; ++i) {
                int id = i * 256 + tid;
                int r = id >> 5, c = id & 31;
                const float* g = Wn + (size_t)(nb * 64 + r) * 256 + c * 8;
                float4 f0 = *(const float4*)g, f1 = *(const float4*)(g + 4);
                *(short8*)&wsh[r * 256 + ((c ^ (r & 7)) * 8)] = pack8(f0, f1);
            }
            __syncthreads();
        }
    }
}

// ---------------- flash attention: 4 waves x 32 Q-rows, KVB=64 -------------
// grid (64, 8), block 256. Each split covers 1024 KV = 16 iters.
__global__ __launch_bounds__(256, 2) void attn_kernel(
    const unsigned short* __restrict__ qb, const unsigned short* __restrict__ kb,
    const unsigned short* __restrict__ vt,
    unsigned short* __restrict__ Opart, float* __restrict__ Mpart,
    float* __restrict__ Lpart)
{
    __shared__ unsigned short Ks[64 * 256];   // 32 KB, chunk-XOR swizzled
    __shared__ unsigned short Vs[256 * 64];   // 32 KB, chunk-XOR swizzled
    __shared__ unsigned short Ps[4][16 * 64]; // 8 KB per-wave P bounce
    const int qblk = blockIdx.x, split = blockIdx.y;
    const int tid = threadIdx.x, wid = tid >> 6, lane = tid & 63;
    const int l15 = lane & 15, kg = lane >> 4;
    const int qrow0 = qblk * 128 + wid * 32;

    // Q fragments for 2 row-tiles (pre-scaled in proj): 64 VGPR
    short8 qf[2][8];
#pragma unroll
    for (int m = 0; m < 2; ++m)
#pragma unroll
        for (int ks = 0; ks < 8; ++ks)
            qf[m][ks] = *(const short8*)(qb + (size_t)(qrow0 + m * 16 + l15) * 256 + ks * 32 + kg * 8);

    f32x4 accO[2][16];  // 128 VGPR
#pragma unroll
    for (int m = 0; m < 2; ++m)
#pragma unroll
        for (int i = 0; i < 16; ++i) accO[m][i] = (f32x4){0.f, 0.f, 0.f, 0.f};
    f32x4 accL[2] = {{0.f, 0.f, 0.f, 0.f}, {0.f, 0.f, 0.f, 0.f}};
    float mrow[2][4];
#pragma unroll
    for (int m = 0; m < 2; ++m)
#pragma unroll
        for (int r = 0; r < 4; ++r) mrow[m][r] = -1e30f;

    short8 ones;
#pragma unroll
    for (int j = 0; j < 8; ++j) ones[j] = (short)0x3F80; // bf16 1.0

    const int kv0 = split * 1024;
    const int r2 = lane >> 5, c32 = lane & 31;  // K-staging lane decomposition
    const int r8 = lane >> 3, c8 = lane & 7;    // V-staging lane decomposition

    for (int t = 0; t < 16; ++t) {
        __syncthreads();  // previous iter's LDS reads done before DMA restage
        // K tile 64x256: 32 wave-instrs of 1KB, 8 per wave (2 rows each).
        // LDS dest linear; source pre-swizzled so swizzled reads see (r, c^(r&7)).
#pragma unroll
        for (int i = 0; i < 8; ++i) {
            const int r0 = (i * 4 + wid) * 2;
            const int row = r0 + r2;
            const int c = c32 ^ (row & 7);
            gl_lds16(kb + (size_t)(kv0 + t * 64 + row) * 256 + c * 8, &Ks[r0 * 256]);
        }
        // V tile 256x64: 8 per wave (8 rows each)
#pragma unroll
        for (int i = 0; i < 8; ++i) {
            const int r0 = (i * 4 + wid) * 8;
            const int row = r0 + r8;
            const int c = c8 ^ (row & 7);
            gl_lds16(vt + (size_t)row * 8192 + kv0 + t * 64 + c * 8, &Vs[r0 * 64]);
        }
        __syncthreads();  // compiler drains vmcnt before barrier

        // S = Q @ K^T  (exp2-domain), both row-tiles share each K fragment
        f32x4 sacc[2][4];
#pragma unroll
        for (int nt = 0; nt < 4; ++nt) {
            f32x4 a0 = {0.f, 0.f, 0.f, 0.f}, a1 = {0.f, 0.f, 0.f, 0.f};
            const int brow = nt * 16 + l15;
#pragma unroll
            for (int ks = 0; ks < 8; ++ks) {
                short8 kf = *(const short8*)&Ks[brow * 256 + (((ks * 4 + kg) ^ (brow & 7)) * 8)];
                a0 = __builtin_amdgcn_mfma_f32_16x16x32_bf16(qf[0][ks], kf, a0, 0, 0, 0);
                a1 = __builtin_amdgcn_mfma_f32_16x16x32_bf16(qf[1][ks], kf, a1, 0, 0, 0);
            }
            sacc[0][nt] = a0; sacc[1][nt] = a1;
        }

        // online softmax with defer-rescale (THR=10 in exp2 domain)
#pragma unroll
        for (int m = 0; m < 2; ++m) {
#pragma unroll
            for (int r = 0; r < 4; ++r) {
                float tm = fmaxf(fmaxf(sacc[m][0][r], sacc[m][1][r]),
                                 fmaxf(sacc[m][2][r], sacc[m][3][r]));
                tm = fmaxf(tm, __shfl_xor(tm, 1));
                tm = fmaxf(tm, __shfl_xor(tm, 2));
                tm = fmaxf(tm, __shfl_xor(tm, 4));
                tm = fmaxf(tm, __shfl_xor(tm, 8));
                const float mo = mrow[m][r];
                if (tm > mo + 10.0f) {       // rescale needed
                    const float alpha = exp2_fast(mo - tm);
#pragma unroll
                    for (int dt = 0; dt < 16; ++dt) accO[m][dt][r] *= alpha;
                    accL[m][r] *= alpha;
                    mrow[m][r] = tm;
                }
                const float mn = mrow[m][r];
#pragma unroll
                for (int nt = 0; nt < 4; ++nt)
                    sacc[m][nt][r] = exp2_fast(sacc[m][nt][r] - mn);
            }
        }

        // P (D-layout) -> wave-private LDS bounce (swizzled) -> A-fragments
        short8 pa[2][2];
#pragma unroll
        for (int m = 0; m < 2; ++m) {
#pragma unroll
            for (int nt = 0; nt < 4; ++nt)
#pragma unroll
                for (int r = 0; r < 4; ++r) {
                    const int row = kg * 4 + r, col = nt * 16 + l15;
                    Ps[wid][row * 64 + (((col >> 3) ^ (row & 7)) * 8) + (col & 7)] =
                        f2bf(sacc[m][nt][r]);
                }
            asm volatile("s_waitcnt lgkmcnt(0)" ::: "memory");
#pragma unroll
            for (int k2 = 0; k2 < 2; ++k2)
                pa[m][k2] = *(const short8*)&Ps[wid][l15 * 64 + (((k2 * 4 + kg) ^ (l15 & 7)) * 8)];
            asm volatile("s_waitcnt lgkmcnt(0)" ::: "memory"); // reads done before rewrite
        }

        // O += P @ V  (V fragments shared across both row-tiles); L via ones-col
#pragma unroll
        for (int dt = 0; dt < 16; ++dt) {
            const int vrow = dt * 16 + l15;
#pragma unroll
            for (int k2 = 0; k2 < 2; ++k2) {
                short8 vf = *(const short8*)&Vs[vrow * 64 + (((k2 * 4 + kg) ^ (vrow & 7)) * 8)];
                accO[0][dt] = __builtin_amdgcn_mfma_f32_16x16x32_bf16(pa[0][k2], vf, accO[0][dt], 0, 0, 0);
                accO[1][dt] = __builtin_amdgcn_mfma_f32_16x16x32_bf16(pa[1][k2], vf, accO[1][dt], 0, 0, 0);
            }
        }
#pragma unroll
        for (int m = 0; m < 2; ++m)
#pragma unroll
            for (int k2 = 0; k2 < 2; ++k2)
                accL[m] = __builtin_amdgcn_mfma_f32_16x16x32_bf16(pa[m][k2], ones, accL[m], 0, 0, 0);
    }

    // partials out (un-normalized, bf16)
#pragma unroll
    for (int m = 0; m < 2; ++m) {
#pragma unroll
        for (int dt = 0; dt < 16; ++dt) {
            const int d = dt * 16 + l15;
#pragma unroll
            for (int r = 0; r < 4; ++r) {
                const int grow = qrow0 + m * 16 + kg * 4 + r;
                Opart[((size_t)split * 8192 + grow) * 256 + d] = f2bf(accO[m][dt][r]);
            }
        }
        if (l15 == 0) {
#pragma unroll
            for (int r = 0; r < 4; ++r) {
                const int grow = qrow0 + m * 16 + kg * 4 + r;
                Mpart[split * 8192 + grow] = mrow[m][r];
                Lpart[split * 8192 + grow] = accL[m][r];
            }
        }
    }
}

// ---------------- combine the 8 KV-split partials --------------------------
__global__ __launch_bounds__(256) void combine_kernel(
    const unsigned short* __restrict__ Opart, const float* __restrict__ Mpart,
    const float* __restrict__ Lpart, float* __restrict__ out)
{
    const int idx = blockIdx.x * 256 + threadIdx.x;  // one float4 each
    const int row = idx >> 6;
    const int d = (idx & 63) * 4;
    float m[8], l[8];
#pragma unroll
    for (int s = 0; s < 8; ++s) {
        m[s] = Mpart[s * 8192 + row];
        l[s] = Lpart[s * 8192 + row];
    }
    float mm = m[0];
#pragma unroll
    for (int s = 1; s < 8; ++s) mm = fmaxf(mm, m[s]);
    float w[8], denom = 0.f;
#pragma unroll
    for (int s = 0; s < 8; ++s) { w[s] = exp2_fast(m[s] - mm); denom += l[s] * w[s]; }
    const float inv = 1.0f / denom;
    float4 acc = {0.f, 0.f, 0.f, 0.f};
#pragma unroll
    for (int s = 0; s < 8; ++s) {
        const unsigned short* p = Opart + ((size_t)s * 8192 + row) * 256 + d;
        unsigned long long u = *(const unsigned long long*)p;
        acc.x += bf2f((unsigned short)(u       & 0xffff)) * w[s];
        acc.y += bf2f((unsigned short)((u>>16) & 0xffff)) * w[s];
        acc.z += bf2f((unsigned short)((u>>32) & 0xffff)) * w[s];
        acc.w += bf2f((unsigned short)((u>>48) & 0xffff)) * w[s];
    }
    float4 r;
    r.x = acc.x * inv; r.y = acc.y * inv; r.z = acc.z * inv; r.w = acc.w * inv;
    *(float4*)(out + (size_t)row * 256 + d) = r;
}

extern "C" void kernel_launch(void* const* d_in, const int* in_sizes, int n_in,
                              void* d_out, int out_size, void* d_ws, size_t ws_size,
                              hipStream_t stream)
{
    const float* x  = (const float*)d_in[0];
    const float* Wq = (const float*)d_in[1];
    const float* Wk = (const float*)d_in[2];
    const float* Wv = (const float*)d_in[3];
    char* ws = (char*)d_ws;
    unsigned short* qb = (unsigned short*)(ws);
    unsigned short* kb = (unsigned short*)(ws + (4u << 20));
    unsigned short* vt = (unsigned short*)(ws + (8u << 20));
    unsigned short* Opart = (unsigned short*)(ws + (12u << 20));
    float* Mpart = (float*)(ws + (44u << 20));
    float* Lpart = (float*)(ws + (44u << 20) + (1u << 18));
    float* out = (float*)d_out;

    dim3 gA(128, 4);
    proj_kernel<<<gA, 256, 0, stream>>>(x, Wq, Wk, Wv, qb, kb, vt);
    dim3 gB(64, 8);
    attn_kernel<<<gB, 256, 0, stream>>>(qb, kb, vt, Opart, Mpart, Lpart);
    combine_kernel<<<2048, 256, 0, stream>>>(Opart, Mpart, Lpart, out);
}

// Round 4
// 228.992 us; speedup vs baseline: 1.0020x; 1.0020x over previous
//
#include <hip/hip_runtime.h>
#include <hip/hip_bf16.h>

// Self-attention, N=8192, C=256, fp32 in/out, bf16 MFMA internally.
// proj (Q,K,V bf16; V transposed; Q pre-scaled by log2e/16)
//   -> flash attention: 32x32x16 MFMA, swapped QK^T (S^T = K@Q^T) so softmax
//      is lane-local; P->A-frag via cvt_pk_bf16 + permlane32_swap (no LDS
//      bounce); reg-staged K/V tiles; split-per-XCD L2 pinning; defer-rescale.
//   -> combine (merge 8 splits, divide by l).
//
// ws: [0,4Mi) qb bf16[8192][256]
//     [4Mi,8Mi) kb bf16[8192][256]
//     [8Mi,12Mi) vt bf16[256][8192]
//     [12Mi,44Mi) Opart bf16[8][8192][256]
//     [44Mi,+256Ki) Mpart f32[8][8192]
//     [+256Ki,+512Ki) Lpart f32[8][8192]     total 44.5 MiB

typedef short short8 __attribute__((ext_vector_type(8)));
typedef float f32x4 __attribute__((ext_vector_type(4)));
typedef float f32x16 __attribute__((ext_vector_type(16)));
typedef unsigned int u32x4 __attribute__((ext_vector_type(4)));

static __device__ __forceinline__ unsigned short f2bf(float f) {
    __hip_bfloat16 h = __float2bfloat16(f);
    return __builtin_bit_cast(unsigned short, h);
}
static __device__ __forceinline__ float bf2f(unsigned short u) {
    unsigned x = ((unsigned)u) << 16;
    return __builtin_bit_cast(float, x);
}
static __device__ __forceinline__ float exp2_fast(float x) {
    float r; asm("v_exp_f32 %0, %1" : "=v"(r) : "v"(x)); return r;
}
static __device__ __forceinline__ unsigned cvt_pk_bf16(float lo, float hi) {
    unsigned r;
    asm("v_cvt_pk_bf16_f32 %0, %1, %2" : "=v"(r) : "v"(lo), "v"(hi));
    return r;
}

static __device__ __forceinline__ short8 pack8(float4 a, float4 b) {
    short8 v;
    v[0] = (short)f2bf(a.x); v[1] = (short)f2bf(a.y);
    v[2] = (short)f2bf(a.z); v[3] = (short)f2bf(a.w);
    v[4] = (short)f2bf(b.x); v[5] = (short)f2bf(b.y);
    v[6] = (short)f2bf(b.z); v[7] = (short)f2bf(b.w);
    return v;
}

// ---------------- projection (unchanged; validated rounds 1-2) -------------
__global__ __launch_bounds__(256) void proj_kernel(
    const float* __restrict__ x, const float* __restrict__ Wq,
    const float* __restrict__ Wk, const float* __restrict__ Wv,
    unsigned short* __restrict__ qb, unsigned short* __restrict__ kb,
    unsigned short* __restrict__ vt)
{
    const int mb = blockIdx.x, nb = blockIdx.y;
    __shared__ unsigned short xs[64 * 256];
    __shared__ unsigned short wsh[64 * 256];
    const int tid = threadIdx.x;
    const int wid = tid >> 6, lane = tid & 63;
    const int l15 = lane & 15, kg = lane >> 4;

    for (int i = 0; i < 8; ++i) {
        int id = i * 256 + tid;
        int r = id >> 5, c = id & 31;
        {
            const float* g = x + (size_t)(mb * 64 + r) * 256 + c * 8;
            float4 f0 = *(const float4*)g, f1 = *(const float4*)(g + 4);
            *(short8*)&xs[r * 256 + ((c ^ (r & 7)) * 8)] = pack8(f0, f1);
        }
        {
            const float* g = Wq + (size_t)(nb * 64 + r) * 256 + c * 8;
            float4 f0 = *(const float4*)g, f1 = *(const float4*)(g + 4);
            *(short8*)&wsh[r * 256 + ((c ^ (r & 7)) * 8)] = pack8(f0, f1);
        }
    }
    __syncthreads();

    const int arow = wid * 16 + l15;
    short8 a[8];
#pragma unroll
    for (int ks = 0; ks < 8; ++ks)
        a[ks] = *(const short8*)&xs[arow * 256 + (((ks * 4 + kg) ^ (arow & 7)) * 8)];

    for (int w = 0; w < 3; ++w) {
        const float scale = (w == 0) ? 0.09016844005555f : 1.0f; // log2(e)/16
#pragma unroll
        for (int nt = 0; nt < 4; ++nt) {
            f32x4 acc = {0.f, 0.f, 0.f, 0.f};
            const int brow = nt * 16 + l15;
#pragma unroll
            for (int ks = 0; ks < 8; ++ks) {
                short8 b = *(const short8*)&wsh[brow * 256 + (((ks * 4 + kg) ^ (brow & 7)) * 8)];
                acc = __builtin_amdgcn_mfma_f32_16x16x32_bf16(a[ks], b, acc, 0, 0, 0);
            }
            const int gcol = nb * 64 + nt * 16 + l15;
#pragma unroll
            for (int r = 0; r < 4; ++r) {
                const int grow = mb * 64 + wid * 16 + kg * 4 + r;
                unsigned short h = f2bf(acc[r] * scale);
                if (w == 0)      qb[(size_t)grow * 256 + gcol] = h;
                else if (w == 1) kb[(size_t)grow * 256 + gcol] = h;
                else             vt[(size_t)gcol * 8192 + grow] = h;
            }
        }
        if (w < 2) {
            __syncthreads();
            const float* Wn = (w == 0) ? Wk : Wv;
            for (int i = 0; i < 8; ++i) {
                int id = i * 256 + tid;
                int r = id >> 5, c = id & 31;
                const float* g = Wn + (size_t)(nb * 64 + r) * 256 + c * 8;
                float4 f0 = *(const float4*)g, f1 = *(const float4*)(g + 4);
                *(short8*)&wsh[r * 256 + ((c ^ (r & 7)) * 8)] = pack8(f0, f1);
            }
            __syncthreads();
        }
    }
}

// ---------------- flash attention: 4 waves x 32 Q-rows, 32x32x16 MFMA ------
// grid 512 flat: split = bid&7 (-> XCD = bid%8, KV slice L2-pinned),
// qblk = bid>>3. Each split covers 1024 KV = 16 iters of KVB=64.
__global__ __launch_bounds__(256, 2) void attn_kernel(
    const unsigned short* __restrict__ qb, const unsigned short* __restrict__ kb,
    const unsigned short* __restrict__ vt,
    unsigned short* __restrict__ Opart, float* __restrict__ Mpart,
    float* __restrict__ Lpart)
{
    __shared__ unsigned short Ks[64 * 256];   // 32 KB, chunk-XOR swizzled
    __shared__ unsigned short Vs[256 * 64];   // 32 KB, chunk-XOR swizzled
    const int bid = blockIdx.x;
    const int split = bid & 7, qblk = bid >> 3;
    const int tid = threadIdx.x, wid = tid >> 6, lane = tid & 63;
    const int l31 = lane & 31, hi = lane >> 5;
    const int qrow0 = qblk * 128 + wid * 32;

    // Q fragments: B-operand layout (col=q=l31, k=hi*8+j per 16-d step). 64 VGPR
    short8 qf[16];
#pragma unroll
    for (int s = 0; s < 16; ++s)
        qf[s] = *(const short8*)(qb + (size_t)(qrow0 + l31) * 256 + s * 16 + hi * 8);

    f32x16 accO[8];
#pragma unroll
    for (int i = 0; i < 8; ++i) accO[i] = (f32x16)(0.f);
    float mrow = -1e30f, lrow = 0.f;

    const int kv0 = split * 1024;

    for (int t = 0; t < 16; ++t) {
        __syncthreads();  // all waves done reading previous tile
        // ---- stage K tile 64x256 (reg-staged, swizzled chunk = c^(r&7)) ----
        {
            short8 kr[8];
#pragma unroll
            for (int i = 0; i < 8; ++i) {
                const int g = i * 256 + tid, r = g >> 5, c = g & 31;
                kr[i] = *(const short8*)(kb + (size_t)(kv0 + t * 64 + r) * 256 + c * 8);
            }
#pragma unroll
            for (int i = 0; i < 8; ++i) {
                const int g = i * 256 + tid, r = g >> 5, c = g & 31;
                *(short8*)&Ks[r * 256 + ((c ^ (r & 7)) * 8)] = kr[i];
            }
        }
        // ---- stage V tile 256x64 ----
        {
            short8 vr[8];
#pragma unroll
            for (int i = 0; i < 8; ++i) {
                const int g = i * 256 + tid, r = g >> 3, c = g & 7;
                vr[i] = *(const short8*)(vt + (size_t)r * 8192 + kv0 + t * 64 + c * 8);
            }
#pragma unroll
            for (int i = 0; i < 8; ++i) {
                const int g = i * 256 + tid, r = g >> 3, c = g & 7;
                *(short8*)&Vs[r * 64 + ((c ^ (r & 7)) * 8)] = vr[i];
            }
        }
        __syncthreads();

        // ---- S^T = K @ Q^T : D col = q (lane-local row softmax) ----
        f32x16 s0 = (f32x16)(0.f), s1 = (f32x16)(0.f);
        __builtin_amdgcn_s_setprio(1);
#pragma unroll
        for (int s = 0; s < 16; ++s) {
            const int cc = s * 2 + hi;
            short8 kf0 = *(const short8*)&Ks[(l31) * 256 + ((cc ^ (l31 & 7)) * 8)];
            short8 kf1 = *(const short8*)&Ks[(32 + l31) * 256 + ((cc ^ (l31 & 7)) * 8)];
            s0 = __builtin_amdgcn_mfma_f32_32x32x16_bf16(kf0, qf[s], s0, 0, 0, 0);
            s1 = __builtin_amdgcn_mfma_f32_32x32x16_bf16(kf1, qf[s], s1, 0, 0, 0);
        }
        __builtin_amdgcn_s_setprio(0);

        // ---- online softmax: lane owns row q=l31 (halves split across hi) --
        float mt[16];
#pragma unroll
        for (int i = 0; i < 16; ++i) mt[i] = fmaxf(s0[i], s1[i]);
#pragma unroll
        for (int off = 8; off >= 1; off >>= 1)
#pragma unroll
            for (int i = 0; i < 8; ++i)
                if (i < off) mt[i] = fmaxf(mt[i], mt[i + off]);
        float mx = fmaxf(mt[0], __shfl_xor(mt[0], 32));

        if (!__all(mx <= mrow + 10.0f)) {   // deferred rescale (T13)
            const float mnew = fmaxf(mrow, mx);
            const float alpha = exp2_fast(mrow - mnew);
            float aR[16];
#pragma unroll
            for (int reg = 0; reg < 16; ++reg) {
                const int R = (reg & 3) + 8 * (reg >> 2) + 4 * hi;
                aR[reg] = __shfl(alpha, R);
            }
#pragma unroll
            for (int dt = 0; dt < 8; ++dt)
#pragma unroll
                for (int reg = 0; reg < 16; ++reg) accO[dt][reg] *= aR[reg];
            lrow *= alpha;
            mrow = mnew;
        }
#pragma unroll
        for (int i = 0; i < 16; ++i) {
            s0[i] = exp2_fast(s0[i] - mrow);
            s1[i] = exp2_fast(s1[i] - mrow);
        }
        float st[16];
#pragma unroll
        for (int i = 0; i < 16; ++i) st[i] = s0[i] + s1[i];
#pragma unroll
        for (int off = 8; off >= 1; off >>= 1)
#pragma unroll
            for (int i = 0; i < 8; ++i)
                if (i < off) st[i] = st[i] + st[i + off];
        lrow += st[0] + __shfl_xor(st[0], 32);

        // ---- P -> A-fragments: cvt_pk pairs + permlane32_swap (no LDS) ----
        // A-frag pa[s]: P[q][s*16 + hi*8 + j], j=0..7.
        // permlane semantics: swap(vdst,vsrc): new_vdst[32+i]=old_vsrc[i],
        // new_vsrc[i]=old_vdst[32+i]. Need hi0.Y <-> hi1.X, so vdst=X, vsrc=Y.
        short8 pa[4];
#pragma unroll
        for (int s = 0; s < 4; ++s) {
            const f32x16& P = (s >> 1) ? s1 : s0;
            const int q0 = 8 * (s & 1);
            unsigned X0 = cvt_pk_bf16(P[q0 + 0], P[q0 + 1]);
            unsigned X1 = cvt_pk_bf16(P[q0 + 2], P[q0 + 3]);
            unsigned Y0 = cvt_pk_bf16(P[q0 + 4], P[q0 + 5]);
            unsigned Y1 = cvt_pk_bf16(P[q0 + 6], P[q0 + 7]);
            asm volatile("v_permlane32_swap_b32 %0, %1" : "+v"(X0), "+v"(Y0));
            asm volatile("v_permlane32_swap_b32 %0, %1" : "+v"(X1), "+v"(Y1));
            u32x4 w = {X0, X1, Y0, Y1};
            pa[s] = __builtin_bit_cast(short8, w);
        }

        // ---- O += P @ V  (A=P from regs, B=V from LDS) ----
        __builtin_amdgcn_s_setprio(1);
#pragma unroll
        for (int dt = 0; dt < 8; ++dt) {
            f32x16 acc = accO[dt];
            const int vrow = dt * 32 + l31;
#pragma unroll
            for (int s = 0; s < 4; ++s) {
                const int cc = s * 2 + hi;
                short8 vf = *(const short8*)&Vs[vrow * 64 + ((cc ^ (vrow & 7)) * 8)];
                acc = __builtin_amdgcn_mfma_f32_32x32x16_bf16(pa[s], vf, acc, 0, 0, 0);
            }
            accO[dt] = acc;
        }
        __builtin_amdgcn_s_setprio(0);
    }

    // ---- partials out (un-normalized, bf16) ----
#pragma unroll
    for (int dt = 0; dt < 8; ++dt) {
        const int d = dt * 32 + l31;
#pragma unroll
        for (int reg = 0; reg < 16; ++reg) {
            const int R = (reg & 3) + 8 * (reg >> 2) + 4 * hi;
            const int grow = qrow0 + R;
            Opart[((size_t)split * 8192 + grow) * 256 + d] = f2bf(accO[dt][reg]);
        }
    }
    if (hi == 0) {
        const int grow = qrow0 + l31;
        Mpart[split * 8192 + grow] = mrow;
        Lpart[split * 8192 + grow] = lrow;
    }
}

// ---------------- combine the 8 KV-split partials --------------------------
__global__ __launch_bounds__(256) void combine_kernel(
    const unsigned short* __restrict__ Opart, const float* __restrict__ Mpart,
    const float* __restrict__ Lpart, float* __restrict__ out)
{
    const int idx = blockIdx.x * 256 + threadIdx.x;  // one float4 each
    const int row = idx >> 6;
    const int d = (idx & 63) * 4;
    float m[8], l[8];
#pragma unroll
    for (int s = 0; s < 8; ++s) {
        m[s] = Mpart[s * 8192 + row];
        l[s] = Lpart[s * 8192 + row];
    }
    float mm = m[0];
#pragma unroll
    for (int s = 1; s < 8; ++s) mm = fmaxf(mm, m[s]);
    float w[8], denom = 0.f;
#pragma unroll
    for (int s = 0; s < 8; ++s) { w[s] = exp2_fast(m[s] - mm); denom += l[s] * w[s]; }
    const float inv = 1.0f / denom;
    float4 acc = {0.f, 0.f, 0.f, 0.f};
#pragma unroll
    for (int s = 0; s < 8; ++s) {
        const unsigned short* p = Opart + ((size_t)s * 8192 + row) * 256 + d;
        unsigned long long u = *(const unsigned long long*)p;
        acc.x += bf2f((unsigned short)(u       & 0xffff)) * w[s];
        acc.y += bf2f((unsigned short)((u>>16) & 0xffff)) * w[s];
        acc.z += bf2f((unsigned short)((u>>32) & 0xffff)) * w[s];
        acc.w += bf2f((unsigned short)((u>>48) & 0xffff)) * w[s];
    }
    float4 r;
    r.x = acc.x * inv; r.y = acc.y * inv; r.z = acc.z * inv; r.w = acc.w * inv;
    *(float4*)(out + (size_t)row * 256 + d) = r;
}

extern "C" void kernel_launch(void* const* d_in, const int* in_sizes, int n_in,
                              void* d_out, int out_size, void* d_ws, size_t ws_size,
                              hipStream_t stream)
{
    const float* x  = (const float*)d_in[0];
    const float* Wq = (const float*)d_in[1];
    const float* Wk = (const float*)d_in[2];
    const float* Wv = (const float*)d_in[3];
    char* ws = (char*)d_ws;
    unsigned short* qb = (unsigned short*)(ws);
    unsigned short* kb = (unsigned short*)(ws + (4u << 20));
    unsigned short* vt = (unsigned short*)(ws + (8u << 20));
    unsigned short* Opart = (unsigned short*)(ws + (12u << 20));
    float* Mpart = (float*)(ws + (44u << 20));
    float* Lpart = (float*)(ws + (44u << 20) + (1u << 18));
    float* out = (float*)d_out;

    dim3 gA(128, 4);
    proj_kernel<<<gA, 256, 0, stream>>>(x, Wq, Wk, Wv, qb, kb, vt);
    attn_kernel<<<512, 256, 0, stream>>>(qb, kb, vt, Opart, Mpart, Lpart);
    combine_kernel<<<2048, 256, 0, stream>>>(Opart, Mpart, Lpart, out);
}

// Round 5
// 125.842 us; speedup vs baseline: 1.8234x; 1.8197x over previous
//
#include <hip/hip_runtime.h>
#include <hip/hip_bf16.h>

// Self-attention, N=8192, C=256, fp32 in/out, bf16 MFMA internally.
// proj (Q,K,V bf16; V transposed; Q pre-scaled by log2e/16)
//   -> flash attention: 512-thr blocks (8 waves x 32 Q-rows), 32x32x16 MFMA,
//      swapped QK^T (lane-local softmax), permlane P-shuffle, double-buffered
//      global_load_lds staging with counted vmcnt (never 0 mid-loop) + raw
//      s_barrier, split-per-XCD L2 pinning, defer-rescale.
//   -> combine (merge 8 splits, divide by l).
//
// ws: [0,4Mi) qb bf16[8192][256]
//     [4Mi,8Mi) kb bf16[8192][256]
//     [8Mi,12Mi) vt bf16[256][8192]
//     [12Mi,44Mi) Opart bf16[8][8192][256]
//     [44Mi,+256Ki) Mpart f32[8][8192]
//     [+256Ki,+512Ki) Lpart f32[8][8192]     total 44.5 MiB

typedef short short8 __attribute__((ext_vector_type(8)));
typedef float f32x4 __attribute__((ext_vector_type(4)));
typedef float f32x16 __attribute__((ext_vector_type(16)));
typedef unsigned int u32x4 __attribute__((ext_vector_type(4)));

#define AS1 __attribute__((address_space(1)))
#define AS3 __attribute__((address_space(3)))

static __device__ __forceinline__ void gl_lds16(const void* g, void* l) {
    __builtin_amdgcn_global_load_lds((const AS1 unsigned int*)g,
                                     (AS3 unsigned int*)l, 16, 0, 0);
}

static __device__ __forceinline__ unsigned short f2bf(float f) {
    __hip_bfloat16 h = __float2bfloat16(f);
    return __builtin_bit_cast(unsigned short, h);
}
static __device__ __forceinline__ float bf2f(unsigned short u) {
    unsigned x = ((unsigned)u) << 16;
    return __builtin_bit_cast(float, x);
}
static __device__ __forceinline__ float exp2_fast(float x) {
    float r; asm("v_exp_f32 %0, %1" : "=v"(r) : "v"(x)); return r;
}
static __device__ __forceinline__ unsigned cvt_pk_bf16(float lo, float hi) {
    unsigned r;
    asm("v_cvt_pk_bf16_f32 %0, %1, %2" : "=v"(r) : "v"(lo), "v"(hi));
    return r;
}

static __device__ __forceinline__ short8 pack8(float4 a, float4 b) {
    short8 v;
    v[0] = (short)f2bf(a.x); v[1] = (short)f2bf(a.y);
    v[2] = (short)f2bf(a.z); v[3] = (short)f2bf(a.w);
    v[4] = (short)f2bf(b.x); v[5] = (short)f2bf(b.y);
    v[6] = (short)f2bf(b.z); v[7] = (short)f2bf(b.w);
    return v;
}

// ---------------- projection (unchanged; validated rounds 1-4) -------------
__global__ __launch_bounds__(256) void proj_kernel(
    const float* __restrict__ x, const float* __restrict__ Wq,
    const float* __restrict__ Wk, const float* __restrict__ Wv,
    unsigned short* __restrict__ qb, unsigned short* __restrict__ kb,
    unsigned short* __restrict__ vt)
{
    const int mb = blockIdx.x, nb = blockIdx.y;
    __shared__ unsigned short xs[64 * 256];
    __shared__ unsigned short wsh[64 * 256];
    const int tid = threadIdx.x;
    const int wid = tid >> 6, lane = tid & 63;
    const int l15 = lane & 15, kg = lane >> 4;

    for (int i = 0; i < 8; ++i) {
        int id = i * 256 + tid;
        int r = id >> 5, c = id & 31;
        {
            const float* g = x + (size_t)(mb * 64 + r) * 256 + c * 8;
            float4 f0 = *(const float4*)g, f1 = *(const float4*)(g + 4);
            *(short8*)&xs[r * 256 + ((c ^ (r & 7)) * 8)] = pack8(f0, f1);
        }
        {
            const float* g = Wq + (size_t)(nb * 64 + r) * 256 + c * 8;
            float4 f0 = *(const float4*)g, f1 = *(const float4*)(g + 4);
            *(short8*)&wsh[r * 256 + ((c ^ (r & 7)) * 8)] = pack8(f0, f1);
        }
    }
    __syncthreads();

    const int arow = wid * 16 + l15;
    short8 a[8];
#pragma unroll
    for (int ks = 0; ks < 8; ++ks)
        a[ks] = *(const short8*)&xs[arow * 256 + (((ks * 4 + kg) ^ (arow & 7)) * 8)];

    for (int w = 0; w < 3; ++w) {
        const float scale = (w == 0) ? 0.09016844005555f : 1.0f; // log2(e)/16
#pragma unroll
        for (int nt = 0; nt < 4; ++nt) {
            f32x4 acc = {0.f, 0.f, 0.f, 0.f};
            const int brow = nt * 16 + l15;
#pragma unroll
            for (int ks = 0; ks < 8; ++ks) {
                short8 b = *(const short8*)&wsh[brow * 256 + (((ks * 4 + kg) ^ (brow & 7)) * 8)];
                acc = __builtin_amdgcn_mfma_f32_16x16x32_bf16(a[ks], b, acc, 0, 0, 0);
            }
            const int gcol = nb * 64 + nt * 16 + l15;
#pragma unroll
            for (int r = 0; r < 4; ++r) {
                const int grow = mb * 64 + wid * 16 + kg * 4 + r;
                unsigned short h = f2bf(acc[r] * scale);
                if (w == 0)      qb[(size_t)grow * 256 + gcol] = h;
                else if (w == 1) kb[(size_t)grow * 256 + gcol] = h;
                else             vt[(size_t)gcol * 8192 + grow] = h;
            }
        }
        if (w < 2) {
            __syncthreads();
            const float* Wn = (w == 0) ? Wk : Wv;
            for (int i = 0; i < 8; ++i) {
                int id = i * 256 + tid;
                int r = id >> 5, c = id & 31;
                const float* g = Wn + (size_t)(nb * 64 + r) * 256 + c * 8;
                float4 f0 = *(const float4*)g, f1 = *(const float4*)(g + 4);
                *(short8*)&wsh[r * 256 + ((c ^ (r & 7)) * 8)] = pack8(f0, f1);
            }
            __syncthreads();
        }
    }
}

// ---------------- flash attention: 8 waves x 32 Q-rows, 32x32x16 MFMA ------
// grid 256 flat: split = bid&7 (XCD-pinned KV slice), qblk = bid>>3.
// Qtile 256/block; split covers 1024 KV = 16 iters of KVB=64.
// Double-buffered LDS (128 KB), global_load_lds DMA, counted vmcnt.
__global__ __launch_bounds__(512, 1) void attn_kernel(
    const unsigned short* __restrict__ qb, const unsigned short* __restrict__ kb,
    const unsigned short* __restrict__ vt,
    unsigned short* __restrict__ Opart, float* __restrict__ Mpart,
    float* __restrict__ Lpart)
{
    __shared__ unsigned short Ks[2][64 * 256];   // 2 x 32 KB
    __shared__ unsigned short Vs[2][256 * 64];   // 2 x 32 KB
    const int bid = blockIdx.x;
    const int split = bid & 7, qblk = bid >> 3;
    const int tid = threadIdx.x, wid = tid >> 6, lane = tid & 63;
    const int l31 = lane & 31, hi = lane >> 5;
    const int qrow0 = qblk * 256 + wid * 32;
    const int kv0 = split * 1024;

    // Q fragments: B-operand layout (col=q=l31, k=hi*8+j per 16-d step). 64 VGPR
    short8 qf[16];
#pragma unroll
    for (int s = 0; s < 16; ++s)
        qf[s] = *(const short8*)(qb + (size_t)(qrow0 + l31) * 256 + s * 16 + hi * 8);

    f32x16 accO[8];
#pragma unroll
    for (int i = 0; i < 8; ++i) accO[i] = (f32x16)(0.f);
    float mrow = -1e30f, lrow = 0.f;

    // staging lane decomposition (per-lane global addr pre-swizzled; LDS linear)
    const int kro = lane >> 5, kc = lane & 31;   // K: 2 rows x 32 chunks / wave-instr
    const int vro = lane >> 3, vc = lane & 7;    // V: 8 rows x 8 chunks / wave-instr

    auto stage = [&](int t, int b) {
        const unsigned short* kbase = kb + (size_t)(kv0 + t * 64) * 256;
#pragma unroll
        for (int i = 0; i < 4; ++i) {
            const int r0 = (i * 8 + wid) * 2;
            const int row = r0 + kro;
            const int c = kc ^ (row & 7);
            gl_lds16(kbase + row * 256 + c * 8, &Ks[b][r0 * 256]);
        }
        const unsigned short* vbase = vt + kv0 + t * 64;
#pragma unroll
        for (int i = 0; i < 4; ++i) {
            const int r0 = (i * 8 + wid) * 8;
            const int row = r0 + vro;
            const int c = vc ^ (row & 7);
            gl_lds16(vbase + (size_t)row * 8192 + c * 8, &Vs[b][r0 * 64]);
        }
    };

    stage(0, 0);

    for (int t = 0; t < 16; ++t) {
        if (t < 15) stage(t + 1, (t + 1) & 1);   // prefetch stays in flight across barrier
        if (t < 15) { asm volatile("s_waitcnt vmcnt(8)" ::: "memory"); }
        else        { asm volatile("s_waitcnt vmcnt(0)" ::: "memory"); }
        __builtin_amdgcn_sched_barrier(0);
        __builtin_amdgcn_s_barrier();            // tile t fully in LDS (all waves)

        const unsigned short* Kb = Ks[t & 1];
        const unsigned short* Vb = Vs[t & 1];

        // ---- S^T = K @ Q^T : D col = q (lane-local row softmax) ----
        f32x16 s0 = (f32x16)(0.f), s1 = (f32x16)(0.f);
        __builtin_amdgcn_s_setprio(1);
#pragma unroll
        for (int s = 0; s < 16; ++s) {
            const int cc = s * 2 + hi;
            short8 kf0 = *(const short8*)&Kb[(l31) * 256 + ((cc ^ (l31 & 7)) * 8)];
            short8 kf1 = *(const short8*)&Kb[(32 + l31) * 256 + ((cc ^ (l31 & 7)) * 8)];
            s0 = __builtin_amdgcn_mfma_f32_32x32x16_bf16(kf0, qf[s], s0, 0, 0, 0);
            s1 = __builtin_amdgcn_mfma_f32_32x32x16_bf16(kf1, qf[s], s1, 0, 0, 0);
        }
        __builtin_amdgcn_s_setprio(0);

        // ---- online softmax: lane owns row q=l31 (halves split across hi) --
        float mt[16];
#pragma unroll
        for (int i = 0; i < 16; ++i) mt[i] = fmaxf(s0[i], s1[i]);
#pragma unroll
        for (int off = 8; off >= 1; off >>= 1)
#pragma unroll
            for (int i = 0; i < 8; ++i)
                if (i < off) mt[i] = fmaxf(mt[i], mt[i + off]);
        float mx = fmaxf(mt[0], __shfl_xor(mt[0], 32));

        if (!__all(mx <= mrow + 10.0f)) {   // deferred rescale (T13)
            const float mnew = fmaxf(mrow, mx);
            const float alpha = exp2_fast(mrow - mnew);
            float aR[16];
#pragma unroll
            for (int reg = 0; reg < 16; ++reg) {
                const int R = (reg & 3) + 8 * (reg >> 2) + 4 * hi;
                aR[reg] = __shfl(alpha, R);
            }
#pragma unroll
            for (int dt = 0; dt < 8; ++dt)
#pragma unroll
                for (int reg = 0; reg < 16; ++reg) accO[dt][reg] *= aR[reg];
            lrow *= alpha;
            mrow = mnew;
        }
#pragma unroll
        for (int i = 0; i < 16; ++i) {
            s0[i] = exp2_fast(s0[i] - mrow);
            s1[i] = exp2_fast(s1[i] - mrow);
        }
        float st[16];
#pragma unroll
        for (int i = 0; i < 16; ++i) st[i] = s0[i] + s1[i];
#pragma unroll
        for (int off = 8; off >= 1; off >>= 1)
#pragma unroll
            for (int i = 0; i < 8; ++i)
                if (i < off) st[i] = st[i] + st[i + off];
        lrow += st[0] + __shfl_xor(st[0], 32);

        // ---- P -> A-fragments: cvt_pk pairs + permlane32_swap (no LDS) ----
        short8 pa[4];
#pragma unroll
        for (int s = 0; s < 4; ++s) {
            const f32x16& P = (s >> 1) ? s1 : s0;
            const int q0 = 8 * (s & 1);
            unsigned X0 = cvt_pk_bf16(P[q0 + 0], P[q0 + 1]);
            unsigned X1 = cvt_pk_bf16(P[q0 + 2], P[q0 + 3]);
            unsigned Y0 = cvt_pk_bf16(P[q0 + 4], P[q0 + 5]);
            unsigned Y1 = cvt_pk_bf16(P[q0 + 6], P[q0 + 7]);
            asm volatile("v_permlane32_swap_b32 %0, %1" : "+v"(X0), "+v"(Y0));
            asm volatile("v_permlane32_swap_b32 %0, %1" : "+v"(X1), "+v"(Y1));
            u32x4 w = {X0, X1, Y0, Y1};
            pa[s] = __builtin_bit_cast(short8, w);
        }

        // ---- O += P @ V  (A=P from regs, B=V from LDS) ----
        __builtin_amdgcn_s_setprio(1);
#pragma unroll
        for (int dt = 0; dt < 8; ++dt) {
            f32x16 acc = accO[dt];
            const int vrow = dt * 32 + l31;
#pragma unroll
            for (int s = 0; s < 4; ++s) {
                const int cc = s * 2 + hi;
                short8 vf = *(const short8*)&Vb[vrow * 64 + ((cc ^ (vrow & 7)) * 8)];
                acc = __builtin_amdgcn_mfma_f32_32x32x16_bf16(pa[s], vf, acc, 0, 0, 0);
            }
            accO[dt] = acc;
        }
        __builtin_amdgcn_s_setprio(0);

        __builtin_amdgcn_s_barrier();            // buf[t&1] free for reuse
    }

    // ---- partials out (un-normalized, bf16) ----
#pragma unroll
    for (int dt = 0; dt < 8; ++dt) {
        const int d = dt * 32 + l31;
#pragma unroll
        for (int reg = 0; reg < 16; ++reg) {
            const int R = (reg & 3) + 8 * (reg >> 2) + 4 * hi;
            const int grow = qrow0 + R;
            Opart[((size_t)split * 8192 + grow) * 256 + d] = f2bf(accO[dt][reg]);
        }
    }
    if (hi == 0) {
        const int grow = qrow0 + l31;
        Mpart[split * 8192 + grow] = mrow;
        Lpart[split * 8192 + grow] = lrow;
    }
}

// ---------------- combine the 8 KV-split partials --------------------------
__global__ __launch_bounds__(256) void combine_kernel(
    const unsigned short* __restrict__ Opart, const float* __restrict__ Mpart,
    const float* __restrict__ Lpart, float* __restrict__ out)
{
    const int idx = blockIdx.x * 256 + threadIdx.x;  // one float4 each
    const int row = idx >> 6;
    const int d = (idx & 63) * 4;
    float m[8], l[8];
#pragma unroll
    for (int s = 0; s < 8; ++s) {
        m[s] = Mpart[s * 8192 + row];
        l[s] = Lpart[s * 8192 + row];
    }
    float mm = m[0];
#pragma unroll
    for (int s = 1; s < 8; ++s) mm = fmaxf(mm, m[s]);
    float w[8], denom = 0.f;
#pragma unroll
    for (int s = 0; s < 8; ++s) { w[s] = exp2_fast(m[s] - mm); denom += l[s] * w[s]; }
    const float inv = 1.0f / denom;
    float4 acc = {0.f, 0.f, 0.f, 0.f};
#pragma unroll
    for (int s = 0; s < 8; ++s) {
        const unsigned short* p = Opart + ((size_t)s * 8192 + row) * 256 + d;
        unsigned long long u = *(const unsigned long long*)p;
        acc.x += bf2f((unsigned short)(u       & 0xffff)) * w[s];
        acc.y += bf2f((unsigned short)((u>>16) & 0xffff)) * w[s];
        acc.z += bf2f((unsigned short)((u>>32) & 0xffff)) * w[s];
        acc.w += bf2f((unsigned short)((u>>48) & 0xffff)) * w[s];
    }
    float4 r;
    r.x = acc.x * inv; r.y = acc.y * inv; r.z = acc.z * inv; r.w = acc.w * inv;
    *(float4*)(out + (size_t)row * 256 + d) = r;
}

extern "C" void kernel_launch(void* const* d_in, const int* in_sizes, int n_in,
                              void* d_out, int out_size, void* d_ws, size_t ws_size,
                              hipStream_t stream)
{
    const float* x  = (const float*)d_in[0];
    const float* Wq = (const float*)d_in[1];
    const float* Wk = (const float*)d_in[2];
    const float* Wv = (const float*)d_in[3];
    char* ws = (char*)d_ws;
    unsigned short* qb = (unsigned short*)(ws);
    unsigned short* kb = (unsigned short*)(ws + (4u << 20));
    unsigned short* vt = (unsigned short*)(ws + (8u << 20));
    unsigned short* Opart = (unsigned short*)(ws + (12u << 20));
    float* Mpart = (float*)(ws + (44u << 20));
    float* Lpart = (float*)(ws + (44u << 20) + (1u << 18));
    float* out = (float*)d_out;

    dim3 gA(128, 4);
    proj_kernel<<<gA, 256, 0, stream>>>(x, Wq, Wk, Wv, qb, kb, vt);
    attn_kernel<<<256, 512, 0, stream>>>(qb, kb, vt, Opart, Mpart, Lpart);
    combine_kernel<<<2048, 256, 0, stream>>>(Opart, Mpart, Lpart, out);
}